// Round 9
// baseline (30496.924 us; speedup 1.0000x reference)
//
#include <hip/hip_runtime.h>
#include <hip/hip_fp16.h>

// ---------------------------------------------------------------------------
// NeuralODE RK4, PERSISTENT kernel v5 (1 wave/SIMD, 512-reg budget).
// R5/R6/R8 post-mortem: at 2 waves/SIMD the 128arch/128agpr split cannot hold
// Y+ACC+A2+frags (~400 regs) under any hand partition -> scratch spill
// dominated (25-43 GB HBM). Fix is geometric, not allocational:
//   - NTHR=256 (4 waves), 131 KiB LDS -> 1 block/CU -> 1 wave/SIMD
//     -> 512-reg unified budget: everything fits with headroom.
//   - per-wave tile 128x64 (m=8, n=4); waves partition columns.
//   - prologue fused into epilogue (k never stored: saves 64 regs + a phase).
//   - Bh-dedup GEMM: phase A = (Ah+Al)xBh sharing one bv load; phase B=AhxBl.
//     Weight traffic/eval 1.125 MiB -> 768 KiB.
//
// f(y) = tanh(relu(relu(y W1+b1) W2'+b2') Wo'+bo')   (BN folded into W2',Wo')
// GEMM precision: bf16 hi/lo 3-term split (AhBh + AlBh + AhBl), ~2^-17 rel.
// ---------------------------------------------------------------------------

typedef unsigned short u16;
typedef unsigned int   u32;
typedef __attribute__((ext_vector_type(8))) short bf16x8;
typedef __attribute__((ext_vector_type(4))) float f32x4;

#define BN_EPS 1e-3f
#define NROWS  65536
#define BM     128
#define NTHR   256
#define WT_ELEMS 131072       // 512*256 per layer: rows [0,256)=Bh, [256,512)=Bl
#define LDS_BIAS 131072       // byte offset of bias region in dynamic LDS
#define LDS_SIZE (131072 + 3072)

__device__ __forceinline__ u16 f2bf(float f) {         // RNE f32 -> bf16 bits
    u32 u = __float_as_uint(f);
    u32 r = u + 0x7FFFu + ((u >> 16) & 1u);
    return (u16)(r >> 16);
}
__device__ __forceinline__ float bf2f(u16 h) {
    return __uint_as_float(((u32)h) << 16);
}
__device__ __forceinline__ float fast_tanh(float x) {
    float e = __expf(2.0f * x);
    return 1.0f - __fdividef(2.0f, e + 1.0f);
}
__device__ __forceinline__ u32 pack_h2(float a, float b) {
    __half2 h = __floats2half2_rn(a, b);
    return *reinterpret_cast<u32*>(&h);
}
__device__ __forceinline__ float2 unpack_h2(u32 v) {
    __half2 h = *reinterpret_cast<__half2*>(&v);
    return __half22float2(h);
}

// LDS act tile [128 rows][512 bf16] (row = [Ah 512B | Al 512B], stride 1KiB).
// XOR swizzle breaks the 16-way bank conflict of the stride-1KiB column read.
#define SWZ(row, kb) (((row) << 10) + ((kb) ^ (((row) & 7) << 4)))

// x -> (hi = trunc16, lo = RNE(residual)) into the act tile (same numerics as
// the benched R5 kernel).
__device__ __forceinline__ void split_store(char* smem, int row, int col2, float x) {
    const u32 xb = __float_as_uint(x);
    *reinterpret_cast<u16*>(smem + SWZ(row, col2)) = (u16)(xb >> 16);
    const float fl = x - __uint_as_float(xb & 0xFFFF0000u);
    *reinterpret_cast<u16*>(smem + SWZ(row, 512 + col2)) = f2bf(fl);
}

// ---------------------------------------------------------------------------
__global__ void prep_bias(const float* __restrict__ b2,
                          const float* __restrict__ g1, const float* __restrict__ be1,
                          const float* __restrict__ m1, const float* __restrict__ v1,
                          const float* __restrict__ W2,
                          const float* __restrict__ bo,
                          const float* __restrict__ g2, const float* __restrict__ be2,
                          const float* __restrict__ m2, const float* __restrict__ v2,
                          const float* __restrict__ Wo,
                          float* __restrict__ b2o, float* __restrict__ boo) {
    int t = threadIdx.x;
    if (t < 256) {
        float s = b2[t];
        for (int i = 0; i < 256; ++i) {
            float s1 = g1[i] * rsqrtf(v1[i] + BN_EPS);
            float t1 = be1[i] - s1 * m1[i];
            s += t1 * W2[i * 256 + t];
        }
        b2o[t] = s;
    } else {
        int j = t - 256;
        float s = bo[j];
        for (int i = 0; i < 256; ++i) {
            float s2 = g2[i] * rsqrtf(v2[i] + BN_EPS);
            float t2 = be2[i] - s2 * m2[i];
            s += t2 * Wo[i * 256 + j];
        }
        boo[j] = s;
    }
}

// scale + split + frag-linear-swizzle weights. kp in [0,512): [Bh | Bl].
// Dest layout per layer: (ks*16+cb)*512 + cc*32 + gg*8 + j  (1KiB coalesced
// per B-frag column-block), ks = kp>>5 in [0,16).
__global__ void prep_weights(const float* __restrict__ W1, const float* __restrict__ W2,
                             const float* __restrict__ Wo,
                             const float* __restrict__ g1, const float* __restrict__ v1,
                             const float* __restrict__ g2, const float* __restrict__ v2,
                             u16* __restrict__ Wt) {
    int tid = blockIdx.x * 256 + threadIdx.x;
    if (tid >= 3 * 512 * 256) return;
    int l   = tid / (512 * 256);
    int r   = tid % (512 * 256);
    int kp  = r >> 8;          // 0..511
    int col = r & 255;
    int ok  = kp & 255;        // original k row
    float w;
    if (l == 0)      w = W1[ok * 256 + col];
    else if (l == 1) w = W2[ok * 256 + col] * (g1[ok] * rsqrtf(v1[ok] + BN_EPS));
    else             w = Wo[ok * 256 + col] * (g2[ok] * rsqrtf(v2[ok] + BN_EPS));
    u16 hi = f2bf(w);
    u16 out = (kp < 256) ? hi : f2bf(w - bf2f(hi));   // [Bh | Bl]
    int ks = kp >> 5, gg = (kp >> 3) & 3, j = kp & 7, cb = col >> 4, cc = col & 15;
    Wt[(size_t)l * WT_ELEMS + ks * 8192 + cb * 512 + cc * 32 + gg * 8 + j] = out;
}

// ---------------------------------------------------------------------------
__global__ __launch_bounds__(NTHR)
__attribute__((amdgpu_waves_per_eu(1, 1)))
void ode_persistent(const float* __restrict__ y0, float* __restrict__ yout,
                    const u16* __restrict__ Wt,
                    const float* __restrict__ b1, const float* __restrict__ b2o,
                    const float* __restrict__ boo) {
    extern __shared__ char smem[];
    float* bias_lds = reinterpret_cast<float*>(smem + LDS_BIAS);
    const int t = threadIdx.x;
    const size_t rowbase = (size_t)blockIdx.x * BM;
    const int lane = t & 63;
    const int wc   = t >> 6;        // 4 waves partition the 256 output cols
    const int c16  = lane & 15, g = lane >> 4;

    // stage biases into LDS (3 x 256 f32)
    for (int i = t; i < 768; i += NTHR) {
        float v = (i < 256) ? b1[i] : ((i < 512) ? b2o[i - 256] : boo[i - 512]);
        bias_lds[i] = v;
    }

    // per-thread state, MFMA C-layout: row = m*16+g*4+j, col = wc*64+n*16+c16
    f32x4 Y [8][4];        // y (128 f32)
    u32   A2[8][4][2];     // RK4 accumulator, packed fp16 pairs (64)

#pragma unroll
    for (int m = 0; m < 8; ++m)
#pragma unroll
        for (int n = 0; n < 4; ++n) {
            const int col = wc * 64 + n * 16 + c16;
#pragma unroll
            for (int j = 0; j < 4; ++j) {
                const int row = m * 16 + g * 4 + j;
                const float v = y0[(rowbase + row) * 256 + col];
                Y[m][n][j] = v;
                split_store(smem, row, col * 2, v);    // x for stage 0 = y
            }
            A2[m][n][0] = 0u; A2[m][n][1] = 0u;
        }
    __syncthreads();

    const float dt  = 1.0f / 40.0f;
    const float c2  = 0.5f * dt;
    const float w16 = dt / 6.0f, w13 = dt / 3.0f;

#pragma unroll 1
    for (int it = 0; it < 160; ++it) {
        const int st = it & 3;
        f32x4 ACC[8][4];

        // ---- 3 layers (rolled) ----
#pragma unroll 1
        for (int l = 0; l < 3; ++l) {
            const u16* __restrict__ wt = Wt + (size_t)l * WT_ELEMS;

#pragma unroll
            for (int n = 0; n < 4; ++n) {
                const float bv = bias_lds[l * 256 + wc * 64 + n * 16 + c16];
                const f32x4 b4 = {bv, bv, bv, bv};
#pragma unroll
                for (int m = 0; m < 8; ++m) ACC[m][n] = b4;
            }

            // phase A: Bh x (Ah + Al) -- one bv load feeds both terms
#pragma unroll 1
            for (int ks = 0; ks < 8; ++ks) {
                const u16* wp = wt + (size_t)(ks * 16 + wc * 4) * 512 + c16 * 32 + g * 8;
                bf16x8 bv[4];
#pragma unroll
                for (int n = 0; n < 4; ++n)
                    bv[n] = *reinterpret_cast<const bf16x8*>(wp + n * 512);
                const int kb = ks * 64 + g * 16;
#pragma unroll
                for (int m = 0; m < 8; ++m) {
                    const int row = m * 16 + c16;
                    const bf16x8 ah = *reinterpret_cast<const bf16x8*>(smem + SWZ(row, kb));
                    const bf16x8 al = *reinterpret_cast<const bf16x8*>(smem + SWZ(row, 512 + kb));
#pragma unroll
                    for (int n = 0; n < 4; ++n)
                        ACC[m][n] = __builtin_amdgcn_mfma_f32_16x16x32_bf16(
                            ah, bv[n], ACC[m][n], 0, 0, 0);
#pragma unroll
                    for (int n = 0; n < 4; ++n)
                        ACC[m][n] = __builtin_amdgcn_mfma_f32_16x16x32_bf16(
                            al, bv[n], ACC[m][n], 0, 0, 0);
                }
            }
            // phase B: Bl x Ah
#pragma unroll 1
            for (int ks = 8; ks < 16; ++ks) {
                const u16* wp = wt + (size_t)(ks * 16 + wc * 4) * 512 + c16 * 32 + g * 8;
                bf16x8 bv[4];
#pragma unroll
                for (int n = 0; n < 4; ++n)
                    bv[n] = *reinterpret_cast<const bf16x8*>(wp + n * 512);
                const int kb = (ks - 8) * 64 + g * 16;
#pragma unroll
                for (int m = 0; m < 8; ++m) {
                    const int row = m * 16 + c16;
                    const bf16x8 ah = *reinterpret_cast<const bf16x8*>(smem + SWZ(row, kb));
#pragma unroll
                    for (int n = 0; n < 4; ++n)
                        ACC[m][n] = __builtin_amdgcn_mfma_f32_16x16x32_bf16(
                            ah, bv[n], ACC[m][n], 0, 0, 0);
                }
            }
            __syncthreads();   // act reads done before overwrite

            if (l < 2) {
                // relu -> hi/lo split -> same LDS tile (next layer's A)
#pragma unroll
                for (int m = 0; m < 8; ++m)
#pragma unroll
                    for (int n = 0; n < 4; ++n) {
                        const int col2 = (wc * 64 + n * 16 + c16) * 2;
#pragma unroll
                        for (int j = 0; j < 4; ++j) {
                            const int row = m * 16 + g * 4 + j;
                            split_store(smem, row, col2, fmaxf(ACC[m][n][j], 0.0f));
                        }
                    }
                __syncthreads();
            }
        }

        // ---- fused epilogue: k = tanh(out); RK4 bookkeeping; write x_next ----
        if (st < 3) {
            const float cn = (st == 2) ? dt : c2;      // c for the NEXT stage
            const float wa = (st == 0) ? w16 : w13;
#pragma unroll
            for (int m = 0; m < 8; ++m)
#pragma unroll
                for (int n = 0; n < 4; ++n) {
                    const int col2 = (wc * 64 + n * 16 + c16) * 2;
                    const float t0 = fast_tanh(ACC[m][n][0]);
                    const float t1 = fast_tanh(ACC[m][n][1]);
                    const float t2 = fast_tanh(ACC[m][n][2]);
                    const float t3 = fast_tanh(ACC[m][n][3]);
                    const float2 p0 = unpack_h2(A2[m][n][0]);
                    const float2 p1 = unpack_h2(A2[m][n][1]);
                    A2[m][n][0] = pack_h2(fmaf(wa, t0, p0.x), fmaf(wa, t1, p0.y));
                    A2[m][n][1] = pack_h2(fmaf(wa, t2, p1.x), fmaf(wa, t3, p1.y));
                    const int r0 = m * 16 + g * 4;
                    split_store(smem, r0 + 0, col2, fmaf(cn, t0, Y[m][n][0]));
                    split_store(smem, r0 + 1, col2, fmaf(cn, t1, Y[m][n][1]));
                    split_store(smem, r0 + 2, col2, fmaf(cn, t2, Y[m][n][2]));
                    split_store(smem, r0 + 3, col2, fmaf(cn, t3, Y[m][n][3]));
                }
        } else {
            // y_new = y + acc + (dt/6)k4 ; x_next = y_new ; acc = 0
#pragma unroll
            for (int m = 0; m < 8; ++m)
#pragma unroll
                for (int n = 0; n < 4; ++n) {
                    const int col2 = (wc * 64 + n * 16 + c16) * 2;
                    const float2 p0 = unpack_h2(A2[m][n][0]);
                    const float2 p1 = unpack_h2(A2[m][n][1]);
                    f32x4 yv = Y[m][n];
                    yv[0] += p0.x + w16 * fast_tanh(ACC[m][n][0]);
                    yv[1] += p0.y + w16 * fast_tanh(ACC[m][n][1]);
                    yv[2] += p1.x + w16 * fast_tanh(ACC[m][n][2]);
                    yv[3] += p1.y + w16 * fast_tanh(ACC[m][n][3]);
                    Y[m][n] = yv;
                    const int r0 = m * 16 + g * 4;
                    split_store(smem, r0 + 0, col2, yv[0]);
                    split_store(smem, r0 + 1, col2, yv[1]);
                    split_store(smem, r0 + 2, col2, yv[2]);
                    split_store(smem, r0 + 3, col2, yv[3]);
                    A2[m][n][0] = 0u; A2[m][n][1] = 0u;
                }
        }
        __syncthreads();   // x_next visible before next eval's layer-0 reads
    }

    // ---- final store ----
#pragma unroll
    for (int m = 0; m < 8; ++m)
#pragma unroll
        for (int n = 0; n < 4; ++n) {
            const int col = wc * 64 + n * 16 + c16;
#pragma unroll
            for (int j = 0; j < 4; ++j) {
                const int row = m * 16 + g * 4 + j;
                yout[(rowbase + row) * 256 + col] = Y[m][n][j];
            }
        }
}

// ---------------------------------------------------------------------------
extern "C" void kernel_launch(void* const* d_in, const int* in_sizes, int n_in,
                              void* d_out, int out_size, void* d_ws, size_t ws_size,
                              hipStream_t stream) {
    const float* y0  = (const float*)d_in[0];
    const float* W1  = (const float*)d_in[1];
    const float* b1  = (const float*)d_in[2];
    const float* g1  = (const float*)d_in[3];
    const float* be1 = (const float*)d_in[4];
    const float* m1  = (const float*)d_in[5];
    const float* v1  = (const float*)d_in[6];
    const float* W2  = (const float*)d_in[7];
    const float* b2  = (const float*)d_in[8];
    const float* g2  = (const float*)d_in[9];
    const float* be2 = (const float*)d_in[10];
    const float* m2  = (const float*)d_in[11];
    const float* v2  = (const float*)d_in[12];
    const float* Wo  = (const float*)d_in[13];
    const float* bo  = (const float*)d_in[14];

    float* y = (float*)d_out;
    char*  ws = (char*)d_ws;
    const size_t MB = 1024 * 1024;
    u16*   Wt   = (u16*)(ws);                 // 3 * 256 KiB
    float* b2o  = (float*)(ws + 1 * MB);
    float* boo  = b2o + 256;

    hipFuncSetAttribute(reinterpret_cast<const void*>(&ode_persistent),
                        hipFuncAttributeMaxDynamicSharedMemorySize, LDS_SIZE);

    prep_bias<<<1, 512, 0, stream>>>(b2, g1, be1, m1, v1, W2,
                                     bo, g2, be2, m2, v2, Wo, b2o, boo);
    prep_weights<<<1536, 256, 0, stream>>>(W1, W2, Wo, g1, v1, g2, v2, Wt);

    ode_persistent<<<NROWS / BM, NTHR, LDS_SIZE, stream>>>(y0, y, Wt, b1, b2o, boo);
}